// Round 3
// baseline (157.441 us; speedup 1.0000x reference)
//
#include <hip/hip_runtime.h>
#include <math.h>

#define B_N 16
#define M_N 64
#define A_N 8400
#define C_N 80
#define TOPK_N 13
#define LIST_CAP 640                 // >= 598 max in-box anchors + 13 pads
#define MAIN_CAP (LIST_CAP - TOPK_N)
#define MSK_W 263                    // ceil(8400/32)

// Anchor centers recomputed from index — bit-exact with numpy f32:
// (j+0.5)*s with s in {8,16,32} (powers of 2, exact). Ravel is row-major:
// a = i*n + j, x = (j+0.5)*s, y = (i+0.5)*s. Level bounds 6400/8000 are
// multiples of 64 -> level is wave-uniform, no divergence.
__device__ __forceinline__ float2 anchor_xy(int a) {
    int i, j; float s;
    if (a < 6400)      { i = a / 80;            j = a - i * 80; s = 8.f;  }
    else if (a < 8000) { int k = a - 6400; i = k / 40; j = k - i * 40; s = 16.f; }
    else               { int k = a - 8000; i = k / 20; j = k - i * 20; s = 32.f; }
    return make_float2(((float)j + 0.5f) * s, ((float)i + 0.5f) * s);
}

// CIoU clipped at 0. Caller guarantees anchor strictly inside gt box
// (so w1,h1 > 0). gt-side terms (w1h1, atan(w1/h1)) hoisted by caller.
__device__ __forceinline__ float ciou_clip(
    float gx1, float gy1, float gx2, float gy2,
    float w1h1, float atg,
    float px1, float py1, float px2, float py2)
{
    float w2 = px2 - px1;
    float h2 = py2 - py1 + 1e-7f;
    float iw = fminf(gx2, px2) - fmaxf(gx1, px1);
    float ih = fminf(gy2, py2) - fmaxf(gy1, py1);
    float inter = fmaxf(iw, 0.f) * fmaxf(ih, 0.f);
    float uni = w1h1 + w2 * h2 - inter + 1e-7f;
    float iou = inter / uni;
    float cw = fmaxf(gx2, px2) - fminf(gx1, px1);
    float ch = fmaxf(gy2, py2) - fminf(gy1, py1);
    float c2 = cw * cw + ch * ch + 1e-7f;
    float dx = px1 + px2 - gx1 - gx2;
    float dy = py1 + py2 - gy1 - gy2;
    float rho2 = (dx * dx + dy * dy) * 0.25f;
    float dat = atanf(w2 / h2) - atg;
    float v = 0.40528473456935109f * (dat * dat);  // 4/pi^2 * dat^2
    float alpha = v / (v - iou + 1.0000001f);
    return fmaxf(iou - (rho2 / c2 + v * alpha), 0.f);
}

// K1: one block per (b,m).
//  pass A: pure-VALU in-box test over all 8400 anchors; ballot-compact
//          in-box indices into s_list; ballot words ARE the anchors_mask.
//  pass B: dense CIoU + score gather over the <=598 compacted entries;
//          pack key = (f32bits(align)<<32) | ((A_N-a)<<1) | emit.
//          Append 13 lowest-index OUT-of-box anchors as zero-valued
//          non-emitting pads — reproduces jax.lax.top_k's zero-tie
//          lowest-index-first semantics exactly when <13 in-box anchors
//          have nonzero metric.
//  select: 13x (scan + wave-butterfly max + 1 LDS atomicMax per wave);
//          owner thread (unique: local best == winner) clears its slot and,
//          if emit, sets bit m of pick[b][a].
__global__ __launch_bounds__(256) void k_topk(
    const float* __restrict__ pd_scores, const float* __restrict__ pd_boxes,
    const int* __restrict__ gt_classes, const float* __restrict__ gt_boxes,
    const int* __restrict__ gt_mask, unsigned long long* __restrict__ pick)
{
    int bm = blockIdx.x;
    if (!gt_mask[bm]) return;               // invalid gt -> no positives
    int b = bm >> 6, m = bm & 63;
    __shared__ unsigned long long s_list[LIST_CAP];
    __shared__ unsigned int s_msk[MSK_W];
    __shared__ unsigned long long s_key[TOPK_N];
    __shared__ int s_n;
    int tid = threadIdx.x;
    int lane = tid & 63;

    const float* g = gt_boxes + (size_t)bm * 4;
    float gx1 = g[0], gy1 = g[1], gx2 = g[2], gy2 = g[3];
    float w1 = gx2 - gx1, h1 = gy2 - gy1 + 1e-7f;
    float w1h1 = w1 * h1;
    float atg = atanf(w1 / h1);

    if (tid == 0) s_n = 0;
    if (tid < TOPK_N) s_key[tid] = 0ull;
    __syncthreads();

    // ---- pass A ----
    for (int a = tid; a < A_N; a += 256) {
        float2 an = anchor_xy(a);
        float dmin = fminf(fminf(an.x - gx1, an.y - gy1),
                           fminf(gx2 - an.x, gy2 - an.y));
        bool inb = dmin > 1e-9f;
        unsigned long long mk = __ballot(inb);
        // wave spans 64 consecutive 64-aligned a -> ballot halves map 1:1
        // onto two s_msk words; every word written exactly once (tail wave
        // inactive lanes contribute 0 bits; word 262 gets only 16 live bits)
        if (lane == 0)       s_msk[a >> 5] = (unsigned int)mk;
        else if (lane == 32) s_msk[a >> 5] = (unsigned int)(mk >> 32);
        if (inb) {
            int ldr = __ffsll(mk) - 1;
            int base = 0;
            if (lane == ldr) base = atomicAdd(&s_n, __popcll(mk));
            base = __shfl(base, ldr, 64);
            int p = base + __popcll(mk & ((1ull << lane) - 1ull));
            if (p < MAIN_CAP)                 // provably never exceeded
                s_list[p] = (unsigned long long)(unsigned int)a;
        }
    }
    __syncthreads();

    // ---- pass B ----
    int n0 = s_n; if (n0 > MAIN_CAP) n0 = MAIN_CAP;
    int cls = gt_classes[bm];
    const float4* pb4 = (const float4*)pd_boxes + (size_t)b * A_N;
    const float* ps = pd_scores + (size_t)b * A_N * C_N + cls;
    for (int p = tid; p < n0; p += 256) {
        int a = (int)(unsigned int)s_list[p];
        float4 pb = pb4[a];
        float io = ciou_clip(gx1, gy1, gx2, gy2, w1h1, atg,
                             pb.x, pb.y, pb.z, pb.w);
        float sc = ps[(size_t)a * C_N];
        float i2 = io * io;
        float al = sc * (i2 * i2 * i2);       // score^1 * iou^6
        s_list[p] = ((unsigned long long)__float_as_uint(al) << 32)
                  | ((unsigned long long)((unsigned int)(A_N - a) << 1)) | 1ull;
    }
    if (tid == 0) {
        // 13 lowest-index out-of-box anchors as zero-valued pads (emit=0);
        // terminates after ~1-2 words (every 80-anchor row has >=59 out-of-box)
        int found = 0;
        for (int wq = 0; wq < MSK_W && found < TOPK_N; ++wq) {
            unsigned int w = ~s_msk[wq];
            if (wq == MSK_W - 1) w &= 0xFFFFu;   // 8400 = 262*32 + 16
            while (w && found < TOPK_N) {
                int bit = __ffs(w) - 1; w &= w - 1;
                int a = wq * 32 + bit;
                s_list[n0 + found] = (unsigned long long)
                                     ((unsigned int)(A_N - a) << 1);
                ++found;
            }
        }
        s_n = n0 + found;                     // always n0 + 13
    }
    __syncthreads();
    int n = s_n;

    // ---- selection ----
    for (int k = 0; k < TOPK_N; ++k) {
        unsigned long long myb = 0ull; int bp = -1;
        for (int p = tid; p < n; p += 256) {
            unsigned long long t = s_list[p];
            if (t > myb) { myb = t; bp = p; }
        }
        unsigned long long wb = myb;
        for (int off = 32; off > 0; off >>= 1) {
            unsigned long long o = __shfl_xor(wb, off, 64);
            if (o > wb) wb = o;
        }
        if (lane == 0 && wb) atomicMax(&s_key[k], wb);
        __syncthreads();
        unsigned long long win = s_key[k];    // nonzero: >=13-k live keys
        if (myb == win && bp >= 0) {          // unique owner (idx in key)
            s_list[bp] = 0ull;
            if (win & 1ull) {
                int idx = A_N - (int)((win >> 1) & 0x7FFFull);
                atomicOr(&pick[(size_t)b * A_N + idx], 1ull << m);
            }
        }
        __syncthreads();
    }
}

// K2: one thread per (b,a). Resolve duplicates (fg>1 -> argmax_m of masked
// clipped ciou over ALL m incl. invalid gts, first-max tie-break ==
// jnp.argmax), emit fg_mask + target_boxes, atomicMax per-(b,m)
// max_align/max_ious (floats >=0 -> uint compare == float compare).
__global__ __launch_bounds__(256) void k_assign(
    const float* __restrict__ pd_scores, const float* __restrict__ pd_boxes,
    const int* __restrict__ gt_classes, const float* __restrict__ gt_boxes,
    const unsigned long long* __restrict__ pick,
    float* __restrict__ out_boxes, float* __restrict__ out_fg,
    int* __restrict__ mtfg, float* __restrict__ alv,
    unsigned int* __restrict__ maxal, unsigned int* __restrict__ maxio)
{
    int i = blockIdx.x * 256 + threadIdx.x;
    if (i >= B_N * A_N) return;
    int b = i / A_N, a = i - b * A_N;
    unsigned long long P = pick[i];
    int fg0 = __popcll(P);
    float2 an = anchor_xy(a);
    float4 pb = ((const float4*)pd_boxes)[i];
    int mt; bool fg;
    if (fg0 > 1) {
        float bestv = -1.f; int bmi = 0;
        for (int mm = 0; mm < M_N; ++mm) {
            const float* g = gt_boxes + ((size_t)b * M_N + mm) * 4;
            float gx1 = g[0], gy1 = g[1], gx2 = g[2], gy2 = g[3];
            float dmin = fminf(fminf(an.x - gx1, an.y - gy1),
                               fminf(gx2 - an.x, gy2 - an.y));
            float v = 0.f;
            if (dmin > 1e-9f) {
                float w1 = gx2 - gx1, h1 = gy2 - gy1 + 1e-7f;
                v = ciou_clip(gx1, gy1, gx2, gy2, w1 * h1, atanf(w1 / h1),
                              pb.x, pb.y, pb.z, pb.w);
            }
            if (v > bestv) { bestv = v; bmi = mm; }
        }
        mt = bmi; fg = true;
    } else {
        fg = (fg0 == 1);
        mt = fg ? (__ffsll(P) - 1) : 0;       // argmax of one-hot / all-false -> 0
    }
    out_fg[i] = fg ? 1.f : 0.f;
    const float* g = gt_boxes + ((size_t)b * M_N + mt) * 4;
    float gx1 = g[0], gy1 = g[1], gx2 = g[2], gy2 = g[3];
    ((float4*)out_boxes)[i] = make_float4(gx1, gy1, gx2, gy2);

    float al = 0.f;
    if (fg) {
        float io = 0.f;
        float dmin = fminf(fminf(an.x - gx1, an.y - gy1),
                           fminf(gx2 - an.x, gy2 - an.y));
        if (dmin > 1e-9f) {   // can be false for dup anchors resolved to m*=0
            float w1 = gx2 - gx1, h1 = gy2 - gy1 + 1e-7f;
            io = ciou_clip(gx1, gy1, gx2, gy2, w1 * h1, atanf(w1 / h1),
                           pb.x, pb.y, pb.z, pb.w);
            float sc = pd_scores[(size_t)i * C_N + gt_classes[b * M_N + mt]];
            float i2 = io * io;
            al = sc * (i2 * i2 * i2);
        }
        atomicMax(&maxal[b * M_N + mt], __float_as_uint(al));
        atomicMax(&maxio[b * M_N + mt], __float_as_uint(io));
    }
    mtfg[i] = mt | (fg ? 256 : 0);
    alv[i] = al;
}

// K3: dense one-hot * norm write, one thread per float4 (20 per row) —
// replaces 43 MB memset + sparse scatter with one coalesced write pass.
// d_out is re-poisoned before every timed call, so every element must be
// written every call.
__global__ __launch_bounds__(256) void k_scores(
    const int* __restrict__ mtfg, const float* __restrict__ alv,
    const unsigned int* __restrict__ maxal,
    const unsigned int* __restrict__ maxio,
    const int* __restrict__ gt_classes, float4* __restrict__ out4)
{
    int i = blockIdx.x * 256 + threadIdx.x;
    if (i >= B_N * A_N * (C_N / 4)) return;
    int row = i / (C_N / 4);
    int q = i - row * (C_N / 4);
    int v = mtfg[row];
    float4 o = make_float4(0.f, 0.f, 0.f, 0.f);
    if (v & 256) {
        int mt = v & 255;
        int b = row / A_N;
        int tc = gt_classes[b * M_N + mt];
        if (tc < 0) tc = 0;
        if ((tc >> 2) == q) {
            float al = alv[row];
            float ma = __uint_as_float(maxal[b * M_N + mt]);
            float mi = __uint_as_float(maxio[b * M_N + mt]);
            ((float*)&o)[tc & 3] = al * mi / (ma + 1e-9f);
        }
    }
    out4[i] = o;
}

extern "C" void kernel_launch(void* const* d_in, const int* in_sizes, int n_in,
                              void* d_out, int out_size, void* d_ws, size_t ws_size,
                              hipStream_t stream) {
    const float* pd_scores  = (const float*)d_in[0];
    const float* pd_boxes   = (const float*)d_in[1];
    // d_in[2] (anchor_tensor) recomputed on-device, bit-exact
    const int*   gt_classes = (const int*)d_in[3];
    const float* gt_boxes   = (const float*)d_in[4];
    const int*   gt_mask    = (const int*)d_in[5];

    float* out = (float*)d_out;
    float* out_scores = out;                                  // B*A*C
    float* out_boxes  = out + (size_t)B_N * A_N * C_N;        // B*A*4
    float* out_fg     = out_boxes + (size_t)B_N * A_N * 4;    // B*A

    char* w = (char*)d_ws;
    unsigned long long* pick = (unsigned long long*)w; w += (size_t)B_N * A_N * 8;
    unsigned int* maxal = (unsigned int*)w;            w += (size_t)B_N * M_N * 4;
    unsigned int* maxio = (unsigned int*)w;            w += (size_t)B_N * M_N * 4;
    int*   mtfg = (int*)w;                             w += (size_t)B_N * A_N * 4;
    float* alv  = (float*)w;

    hipMemsetAsync(pick, 0, (size_t)B_N * A_N * 8, stream);
    hipMemsetAsync(maxal, 0, (size_t)B_N * M_N * 4 * 2, stream);

    k_topk<<<B_N * M_N, 256, 0, stream>>>(pd_scores, pd_boxes, gt_classes,
                                          gt_boxes, gt_mask, pick);

    int na = (B_N * A_N + 255) / 256;
    k_assign<<<na, 256, 0, stream>>>(pd_scores, pd_boxes, gt_classes,
                                     gt_boxes, pick, out_boxes, out_fg,
                                     mtfg, alv, maxal, maxio);

    int ns = (B_N * A_N * (C_N / 4) + 255) / 256;
    k_scores<<<ns, 256, 0, stream>>>(mtfg, alv, maxal, maxio, gt_classes,
                                     (float4*)out_scores);
}

// Round 4
// 154.768 us; speedup vs baseline: 1.0173x; 1.0173x over previous
//
#include <hip/hip_runtime.h>
#include <math.h>

#define B_N 16
#define M_N 64
#define A_N 8400
#define C_N 80
#define TOPK_N 13
#define LIST_CAP 640                 // >= 598 max in-box anchors + 13 pads
#define MAIN_CAP (LIST_CAP - TOPK_N)
#define MSK_W 263                    // ceil(8400/32)

// Anchor centers recomputed from index — bit-exact with numpy f32:
// (j+0.5)*s with s in {8,16,32} (powers of 2, exact). Ravel is row-major:
// a = i*n + j, x = (j+0.5)*s, y = (i+0.5)*s. Level bounds 6400/8000 are
// multiples of 64 -> level is wave-uniform, no divergence.
__device__ __forceinline__ float2 anchor_xy(int a) {
    int i, j; float s;
    if (a < 6400)      { i = a / 80;            j = a - i * 80; s = 8.f;  }
    else if (a < 8000) { int k = a - 6400; i = k / 40; j = k - i * 40; s = 16.f; }
    else               { int k = a - 8000; i = k / 20; j = k - i * 20; s = 32.f; }
    return make_float2(((float)j + 0.5f) * s, ((float)i + 0.5f) * s);
}

// CIoU clipped at 0. Caller guarantees anchor strictly inside gt box
// (so w1,h1 > 0). gt-side terms (w1h1, atan(w1/h1)) hoisted by caller.
__device__ __forceinline__ float ciou_clip(
    float gx1, float gy1, float gx2, float gy2,
    float w1h1, float atg,
    float px1, float py1, float px2, float py2)
{
    float w2 = px2 - px1;
    float h2 = py2 - py1 + 1e-7f;
    float iw = fminf(gx2, px2) - fmaxf(gx1, px1);
    float ih = fminf(gy2, py2) - fmaxf(gy1, py1);
    float inter = fmaxf(iw, 0.f) * fmaxf(ih, 0.f);
    float uni = w1h1 + w2 * h2 - inter + 1e-7f;
    float iou = inter / uni;
    float cw = fmaxf(gx2, px2) - fminf(gx1, px1);
    float ch = fmaxf(gy2, py2) - fminf(gy1, py1);
    float c2 = cw * cw + ch * ch + 1e-7f;
    float dx = px1 + px2 - gx1 - gx2;
    float dy = py1 + py2 - gy1 - gy2;
    float rho2 = (dx * dx + dy * dy) * 0.25f;
    float dat = atanf(w2 / h2) - atg;
    float v = 0.40528473456935109f * (dat * dat);  // 4/pi^2 * dat^2
    float alpha = v / (v - iou + 1.0000001f);
    return fmaxf(iou - (rho2 / c2 + v * alpha), 0.f);
}

// K1: one block per (b,m). (unchanged from passed round-3 version)
//  pass A: pure-VALU in-box test over all 8400 anchors; ballot-compact
//          in-box indices into s_list; ballot words ARE the anchors_mask.
//  pass B: dense CIoU + score gather over the <=598 compacted entries;
//          pack key = (f32bits(align)<<32) | ((A_N-a)<<1) | emit.
//          Append 13 lowest-index OUT-of-box anchors as zero-valued
//          non-emitting pads — reproduces jax.lax.top_k's zero-tie
//          lowest-index-first semantics exactly when <13 in-box anchors
//          have nonzero metric.
//  select: 13x (scan + wave-butterfly max + 1 LDS atomicMax per wave);
//          owner thread (unique: local best == winner) clears its slot and,
//          if emit, sets bit m of pick[b][a].
__global__ __launch_bounds__(256) void k_topk(
    const float* __restrict__ pd_scores, const float* __restrict__ pd_boxes,
    const int* __restrict__ gt_classes, const float* __restrict__ gt_boxes,
    const int* __restrict__ gt_mask, unsigned long long* __restrict__ pick)
{
    int bm = blockIdx.x;
    if (!gt_mask[bm]) return;               // invalid gt -> no positives
    int b = bm >> 6, m = bm & 63;
    __shared__ unsigned long long s_list[LIST_CAP];
    __shared__ unsigned int s_msk[MSK_W];
    __shared__ unsigned long long s_key[TOPK_N];
    __shared__ int s_n;
    int tid = threadIdx.x;
    int lane = tid & 63;

    const float* g = gt_boxes + (size_t)bm * 4;
    float gx1 = g[0], gy1 = g[1], gx2 = g[2], gy2 = g[3];
    float w1 = gx2 - gx1, h1 = gy2 - gy1 + 1e-7f;
    float w1h1 = w1 * h1;
    float atg = atanf(w1 / h1);

    if (tid == 0) s_n = 0;
    if (tid < TOPK_N) s_key[tid] = 0ull;
    __syncthreads();

    // ---- pass A ----
    for (int a = tid; a < A_N; a += 256) {
        float2 an = anchor_xy(a);
        float dmin = fminf(fminf(an.x - gx1, an.y - gy1),
                           fminf(gx2 - an.x, gy2 - an.y));
        bool inb = dmin > 1e-9f;
        unsigned long long mk = __ballot(inb);
        // wave spans 64 consecutive 64-aligned a -> ballot halves map 1:1
        // onto two s_msk words; every word written exactly once (tail wave
        // inactive lanes contribute 0 bits; word 262 gets only 16 live bits)
        if (lane == 0)       s_msk[a >> 5] = (unsigned int)mk;
        else if (lane == 32) s_msk[a >> 5] = (unsigned int)(mk >> 32);
        if (inb) {
            int ldr = __ffsll(mk) - 1;
            int base = 0;
            if (lane == ldr) base = atomicAdd(&s_n, __popcll(mk));
            base = __shfl(base, ldr, 64);
            int p = base + __popcll(mk & ((1ull << lane) - 1ull));
            if (p < MAIN_CAP)                 // provably never exceeded
                s_list[p] = (unsigned long long)(unsigned int)a;
        }
    }
    __syncthreads();

    // ---- pass B ----
    int n0 = s_n; if (n0 > MAIN_CAP) n0 = MAIN_CAP;
    int cls = gt_classes[bm];
    const float4* pb4 = (const float4*)pd_boxes + (size_t)b * A_N;
    const float* ps = pd_scores + (size_t)b * A_N * C_N + cls;
    for (int p = tid; p < n0; p += 256) {
        int a = (int)(unsigned int)s_list[p];
        float4 pb = pb4[a];
        float io = ciou_clip(gx1, gy1, gx2, gy2, w1h1, atg,
                             pb.x, pb.y, pb.z, pb.w);
        float sc = ps[(size_t)a * C_N];
        float i2 = io * io;
        float al = sc * (i2 * i2 * i2);       // score^1 * iou^6
        s_list[p] = ((unsigned long long)__float_as_uint(al) << 32)
                  | ((unsigned long long)((unsigned int)(A_N - a) << 1)) | 1ull;
    }
    if (tid == 0) {
        // 13 lowest-index out-of-box anchors as zero-valued pads (emit=0);
        // terminates after ~1-2 words (every 80-anchor row has >=59 out-of-box)
        int found = 0;
        for (int wq = 0; wq < MSK_W && found < TOPK_N; ++wq) {
            unsigned int w = ~s_msk[wq];
            if (wq == MSK_W - 1) w &= 0xFFFFu;   // 8400 = 262*32 + 16
            while (w && found < TOPK_N) {
                int bit = __ffs(w) - 1; w &= w - 1;
                int a = wq * 32 + bit;
                s_list[n0 + found] = (unsigned long long)
                                     ((unsigned int)(A_N - a) << 1);
                ++found;
            }
        }
        s_n = n0 + found;                     // always n0 + 13
    }
    __syncthreads();
    int n = s_n;

    // ---- selection ----
    for (int k = 0; k < TOPK_N; ++k) {
        unsigned long long myb = 0ull; int bp = -1;
        for (int p = tid; p < n; p += 256) {
            unsigned long long t = s_list[p];
            if (t > myb) { myb = t; bp = p; }
        }
        unsigned long long wb = myb;
        for (int off = 32; off > 0; off >>= 1) {
            unsigned long long o = __shfl_xor(wb, off, 64);
            if (o > wb) wb = o;
        }
        if (lane == 0 && wb) atomicMax(&s_key[k], wb);
        __syncthreads();
        unsigned long long win = s_key[k];    // nonzero: >=13-k live keys
        if (myb == win && bp >= 0) {          // unique owner (idx in key)
            s_list[bp] = 0ull;
            if (win & 1ull) {
                int idx = A_N - (int)((win >> 1) & 0x7FFFull);
                atomicOr(&pick[(size_t)b * A_N + idx], 1ull << m);
            }
        }
        __syncthreads();
    }
}

// K2: one thread per (b,a). (unchanged from passed round-3 version)
__global__ __launch_bounds__(256) void k_assign(
    const float* __restrict__ pd_scores, const float* __restrict__ pd_boxes,
    const int* __restrict__ gt_classes, const float* __restrict__ gt_boxes,
    const unsigned long long* __restrict__ pick,
    float* __restrict__ out_boxes, float* __restrict__ out_fg,
    int* __restrict__ mtfg, float* __restrict__ alv,
    unsigned int* __restrict__ maxal, unsigned int* __restrict__ maxio)
{
    int i = blockIdx.x * 256 + threadIdx.x;
    if (i >= B_N * A_N) return;
    int b = i / A_N, a = i - b * A_N;
    unsigned long long P = pick[i];
    int fg0 = __popcll(P);
    float2 an = anchor_xy(a);
    float4 pb = ((const float4*)pd_boxes)[i];
    int mt; bool fg;
    if (fg0 > 1) {
        // dup anchor: argmax_m of masked clipped ciou over ALL m (incl.
        // invalid gts) — matches reference, which ignores gt_mask here.
        float bestv = -1.f; int bmi = 0;
        for (int mm = 0; mm < M_N; ++mm) {
            const float* g = gt_boxes + ((size_t)b * M_N + mm) * 4;
            float gx1 = g[0], gy1 = g[1], gx2 = g[2], gy2 = g[3];
            float dmin = fminf(fminf(an.x - gx1, an.y - gy1),
                               fminf(gx2 - an.x, gy2 - an.y));
            float v = 0.f;
            if (dmin > 1e-9f) {
                float w1 = gx2 - gx1, h1 = gy2 - gy1 + 1e-7f;
                v = ciou_clip(gx1, gy1, gx2, gy2, w1 * h1, atanf(w1 / h1),
                              pb.x, pb.y, pb.z, pb.w);
            }
            if (v > bestv) { bestv = v; bmi = mm; }
        }
        mt = bmi; fg = true;
    } else {
        fg = (fg0 == 1);
        mt = fg ? (__ffsll(P) - 1) : 0;       // argmax of one-hot / all-false -> 0
    }
    out_fg[i] = fg ? 1.f : 0.f;
    const float* g = gt_boxes + ((size_t)b * M_N + mt) * 4;
    float gx1 = g[0], gy1 = g[1], gx2 = g[2], gy2 = g[3];
    ((float4*)out_boxes)[i] = make_float4(gx1, gy1, gx2, gy2);

    float al = 0.f;
    if (fg) {
        float io = 0.f;
        float dmin = fminf(fminf(an.x - gx1, an.y - gy1),
                           fminf(gx2 - an.x, gy2 - an.y));
        if (dmin > 1e-9f) {   // can be false for dup anchors resolved to m*=0
            float w1 = gx2 - gx1, h1 = gy2 - gy1 + 1e-7f;
            io = ciou_clip(gx1, gy1, gx2, gy2, w1 * h1, atanf(w1 / h1),
                           pb.x, pb.y, pb.z, pb.w);
            float sc = pd_scores[(size_t)i * C_N + gt_classes[b * M_N + mt]];
            float i2 = io * io;
            al = sc * (i2 * i2 * i2);
        }
        atomicMax(&maxal[b * M_N + mt], __float_as_uint(al));
        atomicMax(&maxio[b * M_N + mt], __float_as_uint(io));
    }
    mtfg[i] = mt | (fg ? 256 : 0);
    alv[i] = al;
}

// K3: dense one-hot * norm write. 4 strided float4 per thread (coalesced:
// consecutive lanes hit consecutive float4s on each pass). Grid 2625 blocks
// x 256 threads x 4 = 2,688,000 float4 == B*A*C/4 exactly — no tail.
#define K3_THREADS (B_N * A_N * (C_N / 4) / 4)   // 672000
__global__ __launch_bounds__(256) void k_scores(
    const int* __restrict__ mtfg, const float* __restrict__ alv,
    const unsigned int* __restrict__ maxal,
    const unsigned int* __restrict__ maxio,
    const int* __restrict__ gt_classes, float4* __restrict__ out4)
{
    int i0 = blockIdx.x * 256 + threadIdx.x;
    #pragma unroll
    for (int r = 0; r < 4; ++r) {
        int i = i0 + r * K3_THREADS;
        int row = i / (C_N / 4);
        int q = i - row * (C_N / 4);
        int v = mtfg[row];
        float4 o = make_float4(0.f, 0.f, 0.f, 0.f);
        if (v & 256) {
            int mt = v & 255;
            int b = row / A_N;
            int tc = gt_classes[b * M_N + mt];
            if (tc < 0) tc = 0;
            if ((tc >> 2) == q) {
                float al = alv[row];
                float ma = __uint_as_float(maxal[b * M_N + mt]);
                float mi = __uint_as_float(maxio[b * M_N + mt]);
                ((float*)&o)[tc & 3] = al * mi / (ma + 1e-9f);
            }
        }
        out4[i] = o;
    }
}

extern "C" void kernel_launch(void* const* d_in, const int* in_sizes, int n_in,
                              void* d_out, int out_size, void* d_ws, size_t ws_size,
                              hipStream_t stream) {
    const float* pd_scores  = (const float*)d_in[0];
    const float* pd_boxes   = (const float*)d_in[1];
    // d_in[2] (anchor_tensor) recomputed on-device, bit-exact
    const int*   gt_classes = (const int*)d_in[3];
    const float* gt_boxes   = (const float*)d_in[4];
    const int*   gt_mask    = (const int*)d_in[5];

    float* out = (float*)d_out;
    float* out_scores = out;                                  // B*A*C
    float* out_boxes  = out + (size_t)B_N * A_N * C_N;        // B*A*4
    float* out_fg     = out_boxes + (size_t)B_N * A_N * 4;    // B*A

    char* w = (char*)d_ws;
    unsigned long long* pick = (unsigned long long*)w; w += (size_t)B_N * A_N * 8;
    unsigned int* maxal = (unsigned int*)w;            w += (size_t)B_N * M_N * 4;
    unsigned int* maxio = (unsigned int*)w;            w += (size_t)B_N * M_N * 4;
    int*   mtfg = (int*)w;                             w += (size_t)B_N * A_N * 4;
    float* alv  = (float*)w;

    // pick | maxal | maxio are contiguous -> single zero-fill (one dispatch)
    hipMemsetAsync(pick, 0,
                   (size_t)B_N * A_N * 8 + (size_t)B_N * M_N * 4 * 2, stream);

    k_topk<<<B_N * M_N, 256, 0, stream>>>(pd_scores, pd_boxes, gt_classes,
                                          gt_boxes, gt_mask, pick);

    int na = (B_N * A_N + 255) / 256;
    k_assign<<<na, 256, 0, stream>>>(pd_scores, pd_boxes, gt_classes,
                                     gt_boxes, pick, out_boxes, out_fg,
                                     mtfg, alv, maxal, maxio);

    k_scores<<<K3_THREADS / 256, 256, 0, stream>>>(mtfg, alv, maxal, maxio,
                                                   gt_classes,
                                                   (float4*)out_scores);
}

// Round 12
// 150.371 us; speedup vs baseline: 1.0470x; 1.0292x over previous
//
#include <hip/hip_runtime.h>
#include <math.h>

#define B_N 16
#define M_N 64
#define A_N 8400
#define C_N 80
#define TOPK_N 13
#define LIST_CAP 640                 // >= 598 max in-box anchors + 13 pads
#define MAIN_CAP (LIST_CAP - TOPK_N)
#define MSK_W 263                    // ceil(8400/32)
#define ABLK 33                      // ceil(8400/256) anchor chunks per b

// Anchor centers recomputed from index — bit-exact with numpy f32:
// (j+0.5)*s with s in {8,16,32} (powers of 2, exact). Ravel is row-major:
// a = i*n + j, x = (j+0.5)*s, y = (i+0.5)*s. Level bounds 6400/8000 are
// multiples of 64 -> level is wave-uniform, no divergence.
__device__ __forceinline__ float2 anchor_xy(int a) {
    int i, j; float s;
    if (a < 6400)      { i = a / 80;            j = a - i * 80; s = 8.f;  }
    else if (a < 8000) { int k = a - 6400; i = k / 40; j = k - i * 40; s = 16.f; }
    else               { int k = a - 8000; i = k / 20; j = k - i * 20; s = 32.f; }
    return make_float2(((float)j + 0.5f) * s, ((float)i + 0.5f) * s);
}

// CIoU clipped at 0. Caller guarantees anchor strictly inside gt box
// (so w1,h1 > 0). gt-side terms (w1h1, atan(w1/h1)) hoisted by caller.
__device__ __forceinline__ float ciou_clip(
    float gx1, float gy1, float gx2, float gy2,
    float w1h1, float atg,
    float px1, float py1, float px2, float py2)
{
    float w2 = px2 - px1;
    float h2 = py2 - py1 + 1e-7f;
    float iw = fminf(gx2, px2) - fmaxf(gx1, px1);
    float ih = fminf(gy2, py2) - fmaxf(gy1, py1);
    float inter = fmaxf(iw, 0.f) * fmaxf(ih, 0.f);
    float uni = w1h1 + w2 * h2 - inter + 1e-7f;
    float iou = inter / uni;
    float cw = fmaxf(gx2, px2) - fminf(gx1, px1);
    float ch = fmaxf(gy2, py2) - fminf(gy1, py1);
    float c2 = cw * cw + ch * ch + 1e-7f;
    float dx = px1 + px2 - gx1 - gx2;
    float dy = py1 + py2 - gy1 - gy2;
    float rho2 = (dx * dx + dy * dy) * 0.25f;
    float dat = atanf(w2 / h2) - atg;
    float v = 0.40528473456935109f * (dat * dat);  // 4/pi^2 * dat^2
    float alpha = v / (v - iou + 1.0000001f);
    return fmaxf(iou - (rho2 / c2 + v * alpha), 0.f);
}

// K1: one block per (b,m). Core logic identical to the passed round-3/4
// version; output changed from global-atomicOr bitmask to a compact
// topk_out[bm][13] = (anchor_idx<<1)|emit list (one unique winner-owner
// thread writes each slot). Each block also zero-inits its own
// maxal/maxio slot BEFORE the invalid-gt early-return, replacing the
// hipMemsetAsync dispatch entirely (dup-resolution in K2 can target
// invalid gts, so every slot must be zeroed).
__global__ __launch_bounds__(256) void k_topk(
    const float* __restrict__ pd_scores, const float* __restrict__ pd_boxes,
    const int* __restrict__ gt_classes, const float* __restrict__ gt_boxes,
    const int* __restrict__ gt_mask, int* __restrict__ topk_out,
    unsigned int* __restrict__ maxal, unsigned int* __restrict__ maxio)
{
    int bm = blockIdx.x;
    int tid = threadIdx.x;
    if (tid == 0) { maxal[bm] = 0u; maxio[bm] = 0u; }   // before early-return!
    if (!gt_mask[bm]) return;               // invalid gt -> no picks emitted
    int b = bm >> 6;
    __shared__ unsigned long long s_list[LIST_CAP];
    __shared__ unsigned int s_msk[MSK_W];
    __shared__ unsigned long long s_key[TOPK_N];
    __shared__ int s_n;
    int lane = tid & 63;

    const float* g = gt_boxes + (size_t)bm * 4;
    float gx1 = g[0], gy1 = g[1], gx2 = g[2], gy2 = g[3];
    float w1 = gx2 - gx1, h1 = gy2 - gy1 + 1e-7f;
    float w1h1 = w1 * h1;
    float atg = atanf(w1 / h1);

    if (tid == 0) s_n = 0;
    if (tid < TOPK_N) s_key[tid] = 0ull;
    __syncthreads();

    // ---- pass A: in-box test + ballot-compact; ballot words = anchors_mask
    for (int a = tid; a < A_N; a += 256) {
        float2 an = anchor_xy(a);
        float dmin = fminf(fminf(an.x - gx1, an.y - gy1),
                           fminf(gx2 - an.x, gy2 - an.y));
        bool inb = dmin > 1e-9f;
        unsigned long long mk = __ballot(inb);
        if (lane == 0)       s_msk[a >> 5] = (unsigned int)mk;
        else if (lane == 32) s_msk[a >> 5] = (unsigned int)(mk >> 32);
        if (inb) {
            int ldr = __ffsll(mk) - 1;
            int base = 0;
            if (lane == ldr) base = atomicAdd(&s_n, __popcll(mk));
            base = __shfl(base, ldr, 64);
            int p = base + __popcll(mk & ((1ull << lane) - 1ull));
            if (p < MAIN_CAP)                 // provably never exceeded
                s_list[p] = (unsigned long long)(unsigned int)a;
        }
    }
    __syncthreads();

    // ---- pass B: CIoU + score gather on compacted entries; pack keys
    int n0 = s_n; if (n0 > MAIN_CAP) n0 = MAIN_CAP;
    int cls = gt_classes[bm];
    const float4* pb4 = (const float4*)pd_boxes + (size_t)b * A_N;
    const float* ps = pd_scores + (size_t)b * A_N * C_N + cls;
    for (int p = tid; p < n0; p += 256) {
        int a = (int)(unsigned int)s_list[p];
        float4 pb = pb4[a];
        float io = ciou_clip(gx1, gy1, gx2, gy2, w1h1, atg,
                             pb.x, pb.y, pb.z, pb.w);
        float sc = ps[(size_t)a * C_N];
        float i2 = io * io;
        float al = sc * (i2 * i2 * i2);       // score^1 * iou^6
        s_list[p] = ((unsigned long long)__float_as_uint(al) << 32)
                  | ((unsigned long long)((unsigned int)(A_N - a) << 1)) | 1ull;
    }
    if (tid == 0) {
        // 13 lowest-index OUT-of-box anchors as zero-valued non-emitting
        // pads — reproduces jax.lax.top_k's zero-tie lowest-index-first
        // semantics exactly when <13 in-box anchors have nonzero metric.
        int found = 0;
        for (int wq = 0; wq < MSK_W && found < TOPK_N; ++wq) {
            unsigned int w = ~s_msk[wq];
            if (wq == MSK_W - 1) w &= 0xFFFFu;   // 8400 = 262*32 + 16
            while (w && found < TOPK_N) {
                int bit = __ffs(w) - 1; w &= w - 1;
                int a = wq * 32 + bit;
                s_list[n0 + found] = (unsigned long long)
                                     ((unsigned int)(A_N - a) << 1);
                ++found;
            }
        }
        s_n = n0 + found;                     // always n0 + 13
    }
    __syncthreads();
    int n = s_n;

    // ---- selection: 13x (scan + wave-butterfly max + 1 LDS atomicMax) ----
    for (int k = 0; k < TOPK_N; ++k) {
        unsigned long long myb = 0ull; int bp = -1;
        for (int p = tid; p < n; p += 256) {
            unsigned long long t = s_list[p];
            if (t > myb) { myb = t; bp = p; }
        }
        unsigned long long wb = myb;
        for (int off = 32; off > 0; off >>= 1) {
            unsigned long long o = __shfl_xor(wb, off, 64);
            if (o > wb) wb = o;
        }
        if (lane == 0 && wb) atomicMax(&s_key[k], wb);
        __syncthreads();
        unsigned long long win = s_key[k];    // nonzero: >=13-k live keys
        if (myb == win && bp >= 0) {          // unique owner (idx in key)
            s_list[bp] = 0ull;
            int idx = A_N - (int)((win >> 1) & 0x7FFFull);
            topk_out[bm * TOPK_N + k] = (idx << 1) | (int)(win & 1ull);
        }
        __syncthreads();
    }
}

// K2: one block per (b, 256-anchor chunk); rebuilds the per-anchor 64-bit
// pick mask in LDS from the compact topk_out (gt_mask-filtered — invalid
// gts emit nothing, matching the old global-bitmask path), then runs the
// byte-identical per-anchor logic of the passed round-3/4 version.
__global__ __launch_bounds__(256) void k_assign(
    const float* __restrict__ pd_scores, const float* __restrict__ pd_boxes,
    const int* __restrict__ gt_classes, const float* __restrict__ gt_boxes,
    const int* __restrict__ gt_mask, const int* __restrict__ topk_out,
    float* __restrict__ out_boxes, float* __restrict__ out_fg,
    int* __restrict__ mtfg, float* __restrict__ alv,
    unsigned int* __restrict__ maxal, unsigned int* __restrict__ maxio)
{
    __shared__ unsigned long long s_pick[256];
    int blk = blockIdx.x;
    int b = blk / ABLK;
    int a0 = (blk - b * ABLK) * 256;
    int tid = threadIdx.x;
    s_pick[tid] = 0ull;
    __syncthreads();
    for (int e = tid; e < M_N * TOPK_N; e += 256) {
        int m = e / TOPK_N;
        if (gt_mask[b * M_N + m]) {
            int v = topk_out[b * M_N * TOPK_N + e];
            if (v & 1) {
                int idx = (v >> 1) - a0;
                if ((unsigned)idx < 256u)
                    atomicOr(&s_pick[idx], 1ull << m);
            }
        }
    }
    __syncthreads();
    int a = a0 + tid;
    if (a >= A_N) return;
    int i = b * A_N + a;

    unsigned long long P = s_pick[tid];
    int fg0 = __popcll(P);
    float2 an = anchor_xy(a);
    float4 pb = ((const float4*)pd_boxes)[i];
    int mt; bool fg;
    if (fg0 > 1) {
        // dup anchor: argmax_m of masked clipped ciou over ALL m (incl.
        // invalid gts) — matches reference, which ignores gt_mask here.
        float bestv = -1.f; int bmi = 0;
        for (int mm = 0; mm < M_N; ++mm) {
            const float* g = gt_boxes + ((size_t)b * M_N + mm) * 4;
            float gx1 = g[0], gy1 = g[1], gx2 = g[2], gy2 = g[3];
            float dmin = fminf(fminf(an.x - gx1, an.y - gy1),
                               fminf(gx2 - an.x, gy2 - an.y));
            float v = 0.f;
            if (dmin > 1e-9f) {
                float w1 = gx2 - gx1, h1 = gy2 - gy1 + 1e-7f;
                v = ciou_clip(gx1, gy1, gx2, gy2, w1 * h1, atanf(w1 / h1),
                              pb.x, pb.y, pb.z, pb.w);
            }
            if (v > bestv) { bestv = v; bmi = mm; }
        }
        mt = bmi; fg = true;
    } else {
        fg = (fg0 == 1);
        mt = fg ? (__ffsll(P) - 1) : 0;       // argmax of one-hot / all-false -> 0
    }
    out_fg[i] = fg ? 1.f : 0.f;
    const float* g = gt_boxes + ((size_t)b * M_N + mt) * 4;
    float gx1 = g[0], gy1 = g[1], gx2 = g[2], gy2 = g[3];
    ((float4*)out_boxes)[i] = make_float4(gx1, gy1, gx2, gy2);

    float al = 0.f;
    if (fg) {
        float io = 0.f;
        float dmin = fminf(fminf(an.x - gx1, an.y - gy1),
                           fminf(gx2 - an.x, gy2 - an.y));
        if (dmin > 1e-9f) {   // can be false for dup anchors resolved to m*=0
            float w1 = gx2 - gx1, h1 = gy2 - gy1 + 1e-7f;
            io = ciou_clip(gx1, gy1, gx2, gy2, w1 * h1, atanf(w1 / h1),
                           pb.x, pb.y, pb.z, pb.w);
            float sc = pd_scores[(size_t)i * C_N + gt_classes[b * M_N + mt]];
            float i2 = io * io;
            al = sc * (i2 * i2 * i2);
        }
        atomicMax(&maxal[b * M_N + mt], __float_as_uint(al));
        atomicMax(&maxio[b * M_N + mt], __float_as_uint(io));
    }
    mtfg[i] = mt | (fg ? 256 : 0);
    alv[i] = al;
}

// K3: dense one-hot * norm write. 4 strided float4 per thread (coalesced).
// Grid 2625 blocks x 256 x 4 = 2,688,000 float4 == B*A*C/4 exactly.
// d_out is re-poisoned before every timed call -> every element written.
#define K3_THREADS (B_N * A_N * (C_N / 4) / 4)   // 672000
__global__ __launch_bounds__(256) void k_scores(
    const int* __restrict__ mtfg, const float* __restrict__ alv,
    const unsigned int* __restrict__ maxal,
    const unsigned int* __restrict__ maxio,
    const int* __restrict__ gt_classes, float4* __restrict__ out4)
{
    int i0 = blockIdx.x * 256 + threadIdx.x;
    #pragma unroll
    for (int r = 0; r < 4; ++r) {
        int i = i0 + r * K3_THREADS;
        int row = i / (C_N / 4);
        int q = i - row * (C_N / 4);
        int v = mtfg[row];
        float4 o = make_float4(0.f, 0.f, 0.f, 0.f);
        if (v & 256) {
            int mt = v & 255;
            int b = row / A_N;
            int tc = gt_classes[b * M_N + mt];
            if (tc < 0) tc = 0;
            if ((tc >> 2) == q) {
                float al = alv[row];
                float ma = __uint_as_float(maxal[b * M_N + mt]);
                float mi = __uint_as_float(maxio[b * M_N + mt]);
                ((float*)&o)[tc & 3] = al * mi / (ma + 1e-9f);
            }
        }
        out4[i] = o;
    }
}

extern "C" void kernel_launch(void* const* d_in, const int* in_sizes, int n_in,
                              void* d_out, int out_size, void* d_ws, size_t ws_size,
                              hipStream_t stream) {
    const float* pd_scores  = (const float*)d_in[0];
    const float* pd_boxes   = (const float*)d_in[1];
    // d_in[2] (anchor_tensor) recomputed on-device, bit-exact
    const int*   gt_classes = (const int*)d_in[3];
    const float* gt_boxes   = (const float*)d_in[4];
    const int*   gt_mask    = (const int*)d_in[5];

    float* out = (float*)d_out;
    float* out_scores = out;                                  // B*A*C
    float* out_boxes  = out + (size_t)B_N * A_N * C_N;        // B*A*4
    float* out_fg     = out_boxes + (size_t)B_N * A_N * 4;    // B*A

    char* w = (char*)d_ws;
    int* topk_out = (int*)w;                w += (size_t)B_N * M_N * TOPK_N * 4;
    unsigned int* maxal = (unsigned int*)w; w += (size_t)B_N * M_N * 4;
    unsigned int* maxio = (unsigned int*)w; w += (size_t)B_N * M_N * 4;
    int*   mtfg = (int*)w;                  w += (size_t)B_N * A_N * 4;
    float* alv  = (float*)w;

    // no memsets: k_topk zero-inits maxal/maxio (one slot per block, incl.
    // invalid gts); topk_out poison for invalid gts is gt_mask-filtered in
    // k_assign; k_scores densely overwrites the whole score output.

    k_topk<<<B_N * M_N, 256, 0, stream>>>(pd_scores, pd_boxes, gt_classes,
                                          gt_boxes, gt_mask, topk_out,
                                          maxal, maxio);

    k_assign<<<B_N * ABLK, 256, 0, stream>>>(pd_scores, pd_boxes, gt_classes,
                                             gt_boxes, gt_mask, topk_out,
                                             out_boxes, out_fg,
                                             mtfg, alv, maxal, maxio);

    k_scores<<<K3_THREADS / 256, 256, 0, stream>>>(mtfg, alv, maxal, maxio,
                                                   gt_classes,
                                                   (float4*)out_scores);
}